// Round 3
// baseline (2247.364 us; speedup 1.0000x reference)
//
#include <hip/hip_runtime.h>
#include <stdint.h>

typedef __attribute__((ext_vector_type(8))) short bf16x8;
typedef __attribute__((ext_vector_type(4))) float f32x4;

__device__ __forceinline__ unsigned short f2bf(float f) {
  union { float f; uint32_t u; } v; v.f = f;
  uint32_t u = v.u;
  return (unsigned short)((u + 0x7FFFu + ((u >> 16) & 1u)) >> 16);  // RNE
}

// Fused: out[m][n] = (sum_k x[m][k] * qw[n][k]) * scale[n] + bias[n]
// x fp32 [M][K], qw int32 (int8-valued, exact in bf16) [N][K].
// Single kernel, no workspace, every global access bounds-guarded.
__global__ __launch_bounds__(256) void qgemm_fused(
    const float* __restrict__ X, const int* __restrict__ Q,
    const float* __restrict__ scale, const float* __restrict__ bias,
    float* __restrict__ out,
    int M, int N, int K,
    long long xCount, long long qCount, int sCount, long long oCount) {
  constexpr int BM = 128, BN = 128, BK = 32;
  __shared__ __align__(16) short As[BM * BK];  // 8 KB
  __shared__ __align__(16) short Bs[BN * BK];  // 8 KB

  const int tid  = threadIdx.x;
  const int lane = tid & 63;
  const int wave = tid >> 6;    // 4 waves, 2x2 -> each owns 64x64 of the 128x128 tile
  const int wr   = wave >> 1;
  const int wc   = wave & 1;
  const int bm   = blockIdx.y * BM;
  const int bn   = blockIdx.x * BN;

  f32x4 acc[4][4];
#pragma unroll
  for (int i = 0; i < 4; ++i)
#pragma unroll
    for (int j = 0; j < 4; ++j) acc[i][j] = (f32x4){0.f, 0.f, 0.f, 0.f};

  for (int k0 = 0; k0 < K; k0 += BK) {
    // ---- stage: each thread fills two 16B chunks of each 8KB tile ----
#pragma unroll
    for (int i = 0; i < 2; ++i) {
      int o  = tid * 16 + i * 4096;  // byte offset in tile [0, 8192)
      int r  = o >> 6;               // tile row (64 B = 32 bf16 per row)
      int ce = (o & 63) >> 1;        // element col within row: {0,8,16,24}

      // A chunk: x[bm+r][k0+ce .. +7], fp32 -> bf16
      bf16x8 va;
      long long ax = (long long)(bm + r) * K + (long long)k0 + ce;
      if ((bm + r) < M && (ax + 7) < xCount) {
        float4 f0 = *(const float4*)(X + ax);
        float4 f1 = *(const float4*)(X + ax + 4);
        va[0] = (short)f2bf(f0.x); va[1] = (short)f2bf(f0.y);
        va[2] = (short)f2bf(f0.z); va[3] = (short)f2bf(f0.w);
        va[4] = (short)f2bf(f1.x); va[5] = (short)f2bf(f1.y);
        va[6] = (short)f2bf(f1.z); va[7] = (short)f2bf(f1.w);
      } else {
#pragma unroll
        for (int j = 0; j < 8; ++j) va[j] = 0;
      }
      *(bf16x8*)((char*)As + o) = va;

      // B chunk: qw[bn+r][k0+ce .. +7], int32 (int8-valued) -> bf16 exact
      bf16x8 vb;
      long long bx = (long long)(bn + r) * K + (long long)k0 + ce;
      if ((bn + r) < N && (bx + 7) < qCount) {
        int4 q0 = *(const int4*)(Q + bx);
        int4 q1 = *(const int4*)(Q + bx + 4);
        vb[0] = (short)f2bf((float)q0.x); vb[1] = (short)f2bf((float)q0.y);
        vb[2] = (short)f2bf((float)q0.z); vb[3] = (short)f2bf((float)q0.w);
        vb[4] = (short)f2bf((float)q1.x); vb[5] = (short)f2bf((float)q1.y);
        vb[6] = (short)f2bf((float)q1.z); vb[7] = (short)f2bf((float)q1.w);
      } else {
#pragma unroll
        for (int j = 0; j < 8; ++j) vb[j] = 0;
      }
      *(bf16x8*)((char*)Bs + o) = vb;
    }
    __syncthreads();

    // ---- fragments + MFMA (LDS only; cannot fault) ----
    bf16x8 a[4], b[4];
#pragma unroll
    for (int mi = 0; mi < 4; ++mi) {
      int row = wr * 64 + mi * 16 + (lane & 15);
      a[mi] = *(const bf16x8*)&As[row * BK + ((lane >> 4) << 3)];
    }
#pragma unroll
    for (int ni = 0; ni < 4; ++ni) {
      int row = wc * 64 + ni * 16 + (lane & 15);
      b[ni] = *(const bf16x8*)&Bs[row * BK + ((lane >> 4) << 3)];
    }
#pragma unroll
    for (int mi = 0; mi < 4; ++mi)
#pragma unroll
      for (int ni = 0; ni < 4; ++ni)
        acc[mi][ni] = __builtin_amdgcn_mfma_f32_16x16x32_bf16(a[mi], b[ni], acc[mi][ni], 0, 0, 0);
    __syncthreads();
  }

  // ---- epilogue: out = acc*scale[n] + bias[n]; C/D: col=lane&15, row=(lane>>4)*4+reg ----
#pragma unroll
  for (int ni = 0; ni < 4; ++ni) {
    int col = bn + wc * 64 + ni * 16 + (lane & 15);
    float sc = 0.f, bi = 0.f;
    if (col < N && col < sCount) { sc = scale[col]; bi = bias[col]; }
#pragma unroll
    for (int mi = 0; mi < 4; ++mi) {
      int rbase = bm + wr * 64 + mi * 16 + ((lane >> 4) << 2);
#pragma unroll
      for (int r = 0; r < 4; ++r) {
        int row = rbase + r;
        if (row < M && col < N) {
          long long o = (long long)row * N + col;
          if (o < oCount) out[o] = acc[mi][ni][r] * sc + bi;
        }
      }
    }
  }
}

extern "C" void kernel_launch(void* const* d_in, const int* in_sizes, int n_in,
                              void* d_out, int out_size, void* d_ws, size_t ws_size,
                              hipStream_t stream) {
  (void)d_ws; (void)ws_size; (void)n_in;
  const float* x     = (const float*)d_in[0];
  const int*   qw    = (const int*)d_in[1];
  const float* scale = (const float*)d_in[2];
  const float* bias  = (const float*)d_in[3];
  float* out = (float*)d_out;

  // Derive shapes from actual buffer sizes (no hard-coded assumptions).
  int N = in_sizes[2];                       // scale count = OUT
  int K = (N > 0) ? in_sizes[1] / N : 1;     // qweight = [N][K]
  int M = (K > 0) ? in_sizes[0] / K : 1;     // x = [M][K]

  dim3 grid((N + 127) / 128, (M + 127) / 128);
  qgemm_fused<<<grid, 256, 0, stream>>>(
      x, qw, scale, bias, out, M, N, K,
      (long long)in_sizes[0], (long long)in_sizes[1], in_sizes[2],
      (long long)out_size);
}